// Round 10
// baseline (1729.588 us; speedup 1.0000x reference)
//
#include <hip/hip_runtime.h>

#define BB 64
#define SS 1024
#define HH 512

typedef short short8 __attribute__((ext_vector_type(8)));
typedef float f32x4 __attribute__((ext_vector_type(4)));
typedef _Float16 h2 __attribute__((ext_vector_type(2)));

__device__ inline unsigned short f2bf(float f) {
  unsigned int u = __builtin_bit_cast(unsigned int, f);
  u += 0x7fffu + ((u >> 16) & 1u);   // round-to-nearest-even
  return (unsigned short)(u >> 16);
}

__device__ inline unsigned int pack_h2(float a, float b) {
  unsigned short ua = __builtin_bit_cast(unsigned short, (_Float16)a);
  unsigned short ub = __builtin_bit_cast(unsigned short, (_Float16)b);
  return (unsigned int)ua | ((unsigned int)ub << 16);
}

__device__ inline float dot2a(unsigned int w, unsigned int h, float acc) {
#if __has_builtin(__builtin_amdgcn_fdot2)
  return __builtin_amdgcn_fdot2(__builtin_bit_cast(h2, w),
                                __builtin_bit_cast(h2, h), acc, false);
#else
  h2 a = __builtin_bit_cast(h2, w);
  h2 b = __builtin_bit_cast(h2, h);
  return acc + (float)a[0] * (float)b[0] + (float)a[1] * (float)b[1];
#endif
}

// ---------------------------------------------------------------------------
// Phase 0: pack W_hh rows 192..511 (streamed groups i=3..7) as f16 into d_ws,
// laid out [L][t] so the per-step stream loads are perfectly coalesced.
// L = i_s*8 + j*4 + c (i_s=stream row-group 0..4, j=half 0..1, c=chunk 0..3);
// thread t (kg=t>>6, hg=t&63) owns row hg+64*(3+i_s), k-chunk kg*64+(L&7)*8.
// ---------------------------------------------------------------------------
__global__ __launch_bounds__(512) void pack_ws(
    const float* __restrict__ Whh, uint4* __restrict__ ws4) {
  const int L = blockIdx.x;        // 0..39
  const int t = threadIdx.x;       // 0..511
  const int kg = t >> 6, hg = t & 63;
  const int row = hg + 64 * (3 + (L >> 3));
  const int k0 = kg * 64 + (L & 7) * 8;
  const float* p = Whh + (size_t)row * HH + k0;
  float4 f0 = ((const float4*)p)[0];
  float4 f1 = ((const float4*)p)[1];
  uint4 v;
  v.x = pack_h2(f0.x, f0.y); v.y = pack_h2(f0.z, f0.w);
  v.z = pack_h2(f1.x, f1.y); v.w = pack_h2(f1.z, f1.w);
  ws4[(size_t)L * 512 + t] = v;    // coalesced 16B/lane store
}

// ---------------------------------------------------------------------------
// Phase 1: xt[m, n] = sum_k x[m,k] * W_ih[n,k] + b_ih[n]  (unchanged)
// ---------------------------------------------------------------------------
__global__ __launch_bounds__(256) void xt_gemm(
    const float* __restrict__ x, const float* __restrict__ Wih,
    const float* __restrict__ bih, float* __restrict__ out) {
  __shared__ unsigned short As[64][56];
  __shared__ unsigned short Bs[64][56];

  const int bn = blockIdx.x;  // 0..7
  const int bm = blockIdx.y;  // 0..1023
  const int t = threadIdx.x;
  const int wave = t >> 6, lane = t & 63;
  const int wm = wave >> 1, wn = wave & 1;
  const int m_base = bm * 64, n_base = bn * 64;
  const int sr = t >> 2;
  const int sc = (t & 3) * 8;

  f32x4 acc[2][2] = {};

  for (int k0 = 0; k0 < 512; k0 += 32) {
    __syncthreads();
    {
      const float* p = x + (size_t)(m_base + sr) * 512 + k0 + sc;
      float4 v0 = *(const float4*)p;
      float4 v1 = *(const float4*)(p + 4);
      short8 sa;
      sa[0] = (short)f2bf(v0.x); sa[1] = (short)f2bf(v0.y);
      sa[2] = (short)f2bf(v0.z); sa[3] = (short)f2bf(v0.w);
      sa[4] = (short)f2bf(v1.x); sa[5] = (short)f2bf(v1.y);
      sa[6] = (short)f2bf(v1.z); sa[7] = (short)f2bf(v1.w);
      *(short8*)&As[sr][sc] = sa;

      const float* q = Wih + (size_t)(n_base + sr) * 512 + k0 + sc;
      float4 w0 = *(const float4*)q;
      float4 w1 = *(const float4*)(q + 4);
      short8 sb;
      sb[0] = (short)f2bf(w0.x); sb[1] = (short)f2bf(w0.y);
      sb[2] = (short)f2bf(w0.z); sb[3] = (short)f2bf(w0.w);
      sb[4] = (short)f2bf(w1.x); sb[5] = (short)f2bf(w1.y);
      sb[6] = (short)f2bf(w1.z); sb[7] = (short)f2bf(w1.w);
      *(short8*)&Bs[sr][sc] = sb;
    }
    __syncthreads();

    const int kq = (lane >> 4) * 8;
    short8 a0 = *(const short8*)&As[wm * 32 + (lane & 15)][kq];
    short8 a1 = *(const short8*)&As[wm * 32 + 16 + (lane & 15)][kq];
    short8 b0 = *(const short8*)&Bs[wn * 32 + (lane & 15)][kq];
    short8 b1 = *(const short8*)&Bs[wn * 32 + 16 + (lane & 15)][kq];
    acc[0][0] = __builtin_amdgcn_mfma_f32_16x16x32_bf16(a0, b0, acc[0][0], 0, 0, 0);
    acc[0][1] = __builtin_amdgcn_mfma_f32_16x16x32_bf16(a0, b1, acc[0][1], 0, 0, 0);
    acc[1][0] = __builtin_amdgcn_mfma_f32_16x16x32_bf16(a1, b0, acc[1][0], 0, 0, 0);
    acc[1][1] = __builtin_amdgcn_mfma_f32_16x16x32_bf16(a1, b1, acc[1][1], 0, 0, 0);
  }

#pragma unroll
  for (int ni = 0; ni < 2; ++ni) {
    const int gcol = n_base + wn * 32 + ni * 16 + (lane & 15);
    const float bv = bih[gcol];
#pragma unroll
    for (int mi = 0; mi < 2; ++mi) {
#pragma unroll
      for (int j = 0; j < 4; ++j) {
        const int grow = m_base + wm * 32 + mi * 16 + (lane >> 4) * 4 + j;
        out[(size_t)grow * 512 + gcol] = acc[mi][ni][j] + bv;
      }
    }
  }
}

// ---------------------------------------------------------------------------
// Phase 2: per-batch scan, 512 threads/WG, designed FOR the 128-VGPR grant:
//  - h-state k-span in REGISTERS (8 uint4, loaded via 8 broadcast b128/wave)
//  - weights: group i=0 in regs (32 dw), i=1,2 in LDS (128 KB),
//    i=3..7 STREAMED from pre-packed f16 ws each step (320 KB/CU/step, L2-hot,
//    coalesced dwordx4, 10 half-row batches, 2 in flight = 32 buf regs).
// Ledger: 32h + 32wt + 32buf + ~26 misc = 122 <= 128 -> no spill.
// ---------------------------------------------------------------------------
__global__
__attribute__((amdgpu_flat_work_group_size(512, 512)))
void rnn_scan(const float* __restrict__ Whh, const float* __restrict__ bhh,
              float* __restrict__ out, float* __restrict__ last,
              const uint4* __restrict__ ws4) {
  __shared__ uint4 wlds[16 * 512];        // 128 KB: W row-groups i=1,2
  __shared__ float part[8 * 512];         // 16 KB partials
  __shared__ unsigned short hbuf[512];    // 1 KB h state (f16)

  const int b = blockIdx.x;
  const int t = threadIdx.x;
  const int kg = t >> 6;        // 0..7, wave-uniform
  const int hg = t & 63;
  const int k0 = kg * 64;

  // --- one-time: row-group i=0 into regs ---
  unsigned int wreg[32];
  {
    const float* wr = Whh + (size_t)hg * 512 + k0;
#pragma unroll
    for (int c4 = 0; c4 < 16; ++c4) {
      float4 f = ((const float4*)wr)[c4];
      wreg[c4 * 2]     = pack_h2(f.x, f.y);
      wreg[c4 * 2 + 1] = pack_h2(f.z, f.w);
    }
  }
  // --- one-time: row-groups i=1,2 into LDS ---
#pragma unroll
  for (int i = 1; i < 3; ++i) {
    const float* wr = Whh + (size_t)(hg + 64 * i) * 512 + k0;
#pragma unroll
    for (int c = 0; c < 8; ++c) {
      float4 f0 = ((const float4*)wr)[c * 2];
      float4 f1 = ((const float4*)wr)[c * 2 + 1];
      uint4 v;
      v.x = pack_h2(f0.x, f0.y); v.y = pack_h2(f0.z, f0.w);
      v.z = pack_h2(f1.x, f1.y); v.w = pack_h2(f1.z, f1.w);
      wlds[((i - 1) * 8 + c) * 512 + t] = v;
    }
  }
  if (t < 256) ((unsigned int*)hbuf)[t] = 0;  // h_0 = 0

  float* xt_row = out + (size_t)b * SS * HH;
  float xt_cur = xt_row[t];
  const float bh = bhh[t];
  const uint4* h4 = (const uint4*)hbuf + kg * 8;
  const uint4* wsp = ws4 + t;
  __syncthreads();

#define SLOAD(v0, v1, v2, v3, Lb)        \
  v0 = wsp[((Lb) * 4 + 0) * 512];        \
  v1 = wsp[((Lb) * 4 + 1) * 512];        \
  v2 = wsp[((Lb) * 4 + 2) * 512];        \
  v3 = wsp[((Lb) * 4 + 3) * 512];

  // consume one half-row: buf chunk c pairs with h regs hr[j*4+c]
#define SCONS(v0, v1, v2, v3, ai, j)                              \
  acc_[ai] = dot2a(v0.x, hr[(j) * 4 + 0].x, acc_[ai]);            \
  acc_[ai] = dot2a(v0.y, hr[(j) * 4 + 0].y, acc_[ai]);            \
  acc_[ai] = dot2a(v0.z, hr[(j) * 4 + 0].z, acc_[ai]);            \
  acc_[ai] = dot2a(v0.w, hr[(j) * 4 + 0].w, acc_[ai]);            \
  acc_[ai] = dot2a(v1.x, hr[(j) * 4 + 1].x, acc_[ai]);            \
  acc_[ai] = dot2a(v1.y, hr[(j) * 4 + 1].y, acc_[ai]);            \
  acc_[ai] = dot2a(v1.z, hr[(j) * 4 + 1].z, acc_[ai]);            \
  acc_[ai] = dot2a(v1.w, hr[(j) * 4 + 1].w, acc_[ai]);            \
  acc_[ai] = dot2a(v2.x, hr[(j) * 4 + 2].x, acc_[ai]);            \
  acc_[ai] = dot2a(v2.y, hr[(j) * 4 + 2].y, acc_[ai]);            \
  acc_[ai] = dot2a(v2.z, hr[(j) * 4 + 2].z, acc_[ai]);            \
  acc_[ai] = dot2a(v2.w, hr[(j) * 4 + 2].w, acc_[ai]);            \
  acc_[ai] = dot2a(v3.x, hr[(j) * 4 + 3].x, acc_[ai]);            \
  acc_[ai] = dot2a(v3.y, hr[(j) * 4 + 3].y, acc_[ai]);            \
  acc_[ai] = dot2a(v3.z, hr[(j) * 4 + 3].z, acc_[ai]);            \
  acc_[ai] = dot2a(v3.w, hr[(j) * 4 + 3].w, acc_[ai]);

  for (int step = 0; step < SS; ++step) {
    float xt_next = 0.f;
    if (step + 1 < SS) xt_next = xt_row[(size_t)(step + 1) * HH + t];

    // h-span into registers: 8 broadcast b128 per wave
    uint4 hr[8];
#pragma unroll
    for (int c = 0; c < 8; ++c) hr[c] = hbuf ? h4[c] : hr[c];

    uint4 A0, A1, A2, A3, B0, B1, B2, B3;
    SLOAD(A0, A1, A2, A3, 0);           // stream row-group 3, half 0
    SLOAD(B0, B1, B2, B3, 1);           // stream row-group 3, half 1

    float acc_[8] = {0.f, 0.f, 0.f, 0.f, 0.f, 0.f, 0.f, 0.f};
    // reg row-group i=0
#pragma unroll
    for (int c = 0; c < 8; ++c) {
      acc_[0] = dot2a(wreg[4 * c + 0], hr[c].x, acc_[0]);
      acc_[0] = dot2a(wreg[4 * c + 1], hr[c].y, acc_[0]);
      acc_[0] = dot2a(wreg[4 * c + 2], hr[c].z, acc_[0]);
      acc_[0] = dot2a(wreg[4 * c + 3], hr[c].w, acc_[0]);
    }
    // LDS row-groups i=1,2
#pragma unroll
    for (int c = 0; c < 8; ++c) {
      uint4 w1 = wlds[c * 512 + t];
      uint4 w2 = wlds[(8 + c) * 512 + t];
      acc_[1] = dot2a(w1.x, hr[c].x, acc_[1]);
      acc_[1] = dot2a(w1.y, hr[c].y, acc_[1]);
      acc_[1] = dot2a(w1.z, hr[c].z, acc_[1]);
      acc_[1] = dot2a(w1.w, hr[c].w, acc_[1]);
      acc_[2] = dot2a(w2.x, hr[c].x, acc_[2]);
      acc_[2] = dot2a(w2.y, hr[c].y, acc_[2]);
      acc_[2] = dot2a(w2.z, hr[c].z, acc_[2]);
      acc_[2] = dot2a(w2.w, hr[c].w, acc_[2]);
    }
    // streamed row-groups i=3..7: consume/issue pipelined, 2 batches in flight
    SCONS(A0, A1, A2, A3, 3, 0); SLOAD(A0, A1, A2, A3, 2);
    SCONS(B0, B1, B2, B3, 3, 1); SLOAD(B0, B1, B2, B3, 3);
    SCONS(A0, A1, A2, A3, 4, 0); SLOAD(A0, A1, A2, A3, 4);
    SCONS(B0, B1, B2, B3, 4, 1); SLOAD(B0, B1, B2, B3, 5);
    SCONS(A0, A1, A2, A3, 5, 0); SLOAD(A0, A1, A2, A3, 6);
    SCONS(B0, B1, B2, B3, 5, 1); SLOAD(B0, B1, B2, B3, 7);
    SCONS(A0, A1, A2, A3, 6, 0); SLOAD(A0, A1, A2, A3, 8);
    SCONS(B0, B1, B2, B3, 6, 1); SLOAD(B0, B1, B2, B3, 9);
    SCONS(A0, A1, A2, A3, 7, 0);
    SCONS(B0, B1, B2, B3, 7, 1);

    // partial store: per wave, 64 consecutive dwords per i -> conflict-free
#pragma unroll
    for (int i = 0; i < 8; ++i) part[kg * 512 + hg + 64 * i] = acc_[i];
    __syncthreads();

    // finalize: all 512 threads, h = t
    float y = xt_cur + bh;
#pragma unroll
    for (int g = 0; g < 8; ++g) y += part[g * 512 + t];
    float ht = tanhf(y);
    xt_row[(size_t)step * HH + t] = ht;  // overwrite xt with output h
    hbuf[t] = __builtin_bit_cast(unsigned short, (_Float16)ht);
    xt_cur = xt_next;
    __syncthreads();
  }

  last[(size_t)b * HH + t] = xt_row[(size_t)(SS - 1) * HH + t];
#undef SLOAD
#undef SCONS
}

extern "C" void kernel_launch(void* const* d_in, const int* in_sizes, int n_in,
                              void* d_out, int out_size, void* d_ws, size_t ws_size,
                              hipStream_t stream) {
  (void)in_sizes; (void)n_in; (void)ws_size; (void)out_size;
  const float* x   = (const float*)d_in[0];
  const float* Wih = (const float*)d_in[1];
  const float* bih = (const float*)d_in[2];
  const float* Whh = (const float*)d_in[3];
  const float* bhh = (const float*)d_in[4];
  float* out  = (float*)d_out;
  float* last = out + (size_t)BB * SS * HH;
  uint4* ws4  = (uint4*)d_ws;   // 320 KB: pre-packed f16 stream layout

  // Phase 0: pack streamed W rows (f16, [L][t] coalesced layout)
  pack_ws<<<40, 512, 0, stream>>>(Whh, ws4);

  // Phase 1: input projection for all timesteps -> d_out (in-place xt buffer)
  xt_gemm<<<dim3(8, 1024), 256, 0, stream>>>(x, Wih, bih, out);

  // Phase 2: 64 sync-free per-batch chains, 145 KB static LDS each
  rnn_scan<<<64, 512, 0, stream>>>(Whh, bhh, out, last, ws4);
}